// Round 14
// baseline (610.525 us; speedup 1.0000x reference)
//
#include <hip/hip_runtime.h>
#include <hip/hip_fp8.h>

typedef unsigned char u8;
typedef unsigned short u16;
typedef long lng2 __attribute__((ext_vector_type(2)));
typedef float f32x4 __attribute__((ext_vector_type(4)));
typedef u16 u16x8 __attribute__((ext_vector_type(8)));
typedef u8 u8x16 __attribute__((ext_vector_type(16)));

#define HW_N 16384   // 128*128 pixels
#define NCH  2048
// A8 layout: [kc 0..32][pixel 16384][64 bytes]  fp8 e4m3, k-interleaved:
//   byte b holds k = (b&15)<8 ? (b>>4)*8+(b&7) : 32+(b>>4)*8+(b&7)
// W8 layout: [kc][ch 2048][64 bytes], same permutation, values pre-scaled x16
// Wd8 layout: [kc 0..31][j 48][64 bytes], x16
// LDS swizzle (k_gemm/k_dense): LDS[row][c] = global[row][c ^ ((row>>1)&3)]
//   (write via pre-swizzled gload source; read chunk = kgrp ^ ((r16>>1)&3))

__device__ __forceinline__ u16 f2bf(float f) {
  union { float f; unsigned u; } v; v.f = f;
  unsigned r = v.u + 0x7FFFu + ((v.u >> 16) & 1u);
  return (u16)(r >> 16);
}
__device__ __forceinline__ float bf2f(u16 u) {
  union { unsigned u; float f; } v; v.u = ((unsigned)u) << 16; return v.f;
}
__device__ __forceinline__ u8 f2fp8(float f) {
  __hip_fp8_e4m3 t(f);
  return (u8)t.__x;
}
__device__ __forceinline__ float lrelu(float v) { return v >= 0.0f ? v : 0.2f * v; }

__device__ __forceinline__ void gload_lds16(const u8* g, u8* l) {
  __builtin_amdgcn_global_load_lds((const __attribute__((address_space(1))) void*)g,
                                   (__attribute__((address_space(3))) void*)l, 16, 0, 0);
}

// ---------------- kernel 1: LN stats + pooled partial + coalesced fp8 A copy ----------------
__global__ __launch_bounds__(256) void k_stats(const float* __restrict__ trans,
                                               u8* __restrict__ A8,
                                               float* __restrict__ pooled_sum) {
  const int z = blockIdx.x;
  const int tid = threadIdx.x;
  const int ptile = blockIdx.y;
  const int p = ptile * 256 + tid;
  const float* src = trans + (size_t)z * 64 * HW_N + p;
  float x[64];
#pragma unroll
  for (int c = 0; c < 64; ++c) x[c] = src[(size_t)c * HW_N];
  float sum = 0.f, sq = 0.f;
#pragma unroll
  for (int c = 0; c < 64; ++c) { sum += x[c]; sq += x[c] * x[c]; }
  const float mu = sum * (1.0f / 64.0f);
  const float var = sq * (1.0f / 64.0f) - mu * mu;
  const float rstd = rsqrtf(var + 1e-5f);

  __shared__ __align__(16) u8 rawt[256 * 64];    // 16 KB fp8 (permuted)
  __shared__ __align__(16) u16 normt[256 * 64];  // 32 KB bf16 (pooling path)
  const int r3m = tid & 3, r7 = tid & 7;
#pragma unroll
  for (int c = 0; c < 4; ++c) {
    u8x16 y;
#pragma unroll
    for (int w = 0; w < 16; ++w) {
      const int k = (w < 8) ? (c * 8 + w) : (32 + c * 8 + (w - 8));
      y[w] = f2fp8(x[k]);
    }
    *(u8x16*)&rawt[tid * 64 + ((c ^ r3m) << 4)] = y;
  }
#pragma unroll
  for (int c8 = 0; c8 < 8; ++c8) {
    u16x8 wn;
#pragma unroll
    for (int e = 0; e < 8; ++e) wn[e] = f2bf((x[c8 * 8 + e] - mu) * rstd);
    *(u16x8*)&normt[tid * 64 + ((c8 ^ r7) << 3)] = wn;
  }
  __syncthreads();

  // coalesced writeout of 16 KB fp8 tile (global stays canonical-interleaved)
  u8* gbase = A8 + ((size_t)z * HW_N + (size_t)ptile * 256) * 64;
#pragma unroll
  for (int it = 0; it < 4; ++it) {
    const int o = it * 256 + tid;
    const int row = o >> 2, c4 = o & 3;
    *(u8x16*)(gbase + o * 16) = *(const u8x16*)&rawt[row * 64 + ((c4 ^ (row & 3)) << 4)];
  }

  // pooled[z][c] partial from norm tile
  const int c = tid & 63, q = tid >> 6;
  const int kc2 = c >> 3, e2 = c & 7;
  float s = 0.f;
#pragma unroll 8
  for (int i = 0; i < 64; ++i) {
    const int row = q * 64 + i;
    s += bf2f(normt[row * 64 + ((kc2 ^ (row & 7)) << 3) + e2]);
  }
  __shared__ float red2[4][64];
  red2[q][c] = s;
  __syncthreads();
  if (tid < 64) {
    atomicAdd(&pooled_sum[z * 64 + tid],
              red2[0][tid] + red2[1][tid] + red2[2][tid] + red2[3][tid]);
  }
}

// ---------------- kernel 2: pack fuse_w -> W8 AND dense weights -> Wd8 (one dispatch) --------
__global__ __launch_bounds__(256) void k_wpack(const float* __restrict__ fw,
                                               const float* __restrict__ dw0,
                                               const float* __restrict__ dw1,
                                               const float* __restrict__ dw2,
                                               u8* __restrict__ W8,
                                               u8* __restrict__ Wd8) {
  __shared__ float tile[64][65];
  const int tid = threadIdx.x;
  const int ktile = blockIdx.x;
  const int yb = blockIdx.y;
  if (yb == 32) {
    const int kc = ktile;
    if (kc >= 32) return;
    for (int idx = tid; idx < 3072; idx += 256) {
      const int kk = idx / 48, j = idx % 48;
      const int k = kc * 64 + kk;
      float v = (j < 16) ? dw0[k * 16 + j]
              : (j < 32) ? dw1[k * 16 + (j - 16)]
                         : dw2[k * 16 + (j - 32)];
      tile[kk][j] = v;
    }
    __syncthreads();
    for (int idx = tid; idx < 3072; idx += 256) {
      const int j = idx / 64, kk = idx % 64;
      const int pos = ((kk >> 3) & 3) * 16 + (kk & 7) + ((kk >> 5) << 3);
      Wd8[((size_t)kc * 48 + j) * 64 + pos] = f2fp8(16.0f * tile[kk][j]);
    }
    return;
  }
  const int ntile = yb;
  {
    const int kk0 = tid >> 6, nn = tid & 63;
#pragma unroll
    for (int it = 0; it < 16; ++it) {
      int kk = it * 4 + kk0;
      int kg = ktile * 64 + kk;
      tile[kk][nn] = (kg < 2096) ? fw[(size_t)kg * NCH + ntile * 64 + nn] : 0.0f;
    }
  }
  __syncthreads();
  {
    const int kk = tid & 63, nn0 = tid >> 6;
    const int pos = ((kk >> 3) & 3) * 16 + (kk & 7) + ((kk >> 5) << 3);
#pragma unroll
    for (int it = 0; it < 16; ++it) {
      int n = it * 4 + nn0;
      W8[((size_t)ktile * NCH + ntile * 64 + n) * 64 + pos] = f2fp8(16.0f * tile[kk][n]);
    }
  }
}

// ---------------- kernel 3: dense chain fused (GEMM full K + f0/f1/f2 + pack slab 32) --------
__global__ __launch_bounds__(256) void k_dense(const u8* __restrict__ A8,
    const u8* __restrict__ Wd8,
    const float* __restrict__ dw1, const float* __restrict__ dw2,
    const float* __restrict__ db0, const float* __restrict__ db1,
    const float* __restrict__ db2, u8* __restrict__ A8out) {
  __shared__ __align__(16) u8 lsA[128 * 64];  // 8 KB
  __shared__ __align__(16) u8 lsW[48 * 64];   // 3 KB
  __shared__ float trn[128][49];              // 24.5 KB
  __shared__ float w1t[16][16];
  __shared__ float w2t[32][16];
  __shared__ float biases[48];
  const int tid = threadIdx.x;
  const int lane = tid & 63;
  const int wave = __builtin_amdgcn_readfirstlane(tid >> 6);
  const int mb = blockIdx.x;
  const int r16 = lane & 15, kgrp = lane >> 4;
  const int sgoff8 = ((lane >> 2) << 6) + (((lane & 3) ^ ((lane >> 3) & 3)) << 4);
  const int kx = (kgrp ^ ((r16 >> 1) & 3)) << 4;

  if (tid < 256) w1t[tid >> 4][tid & 15] = dw1[(2048 + (tid >> 4)) * 16 + (tid & 15)];
  for (int idx = tid; idx < 512; idx += 256)
    w2t[idx >> 4][idx & 15] = dw2[(2048 + (idx >> 4)) * 16 + (idx & 15)];
  if (tid < 48) biases[tid] = (tid < 16) ? db0[tid] : (tid < 32) ? db1[tid - 16] : db2[tid - 32];

  f32x4 acc[3][2] = {};
  for (int t = 0; t < 32; ++t) {
    const u8* slabA = A8 + ((size_t)t * HW_N + (size_t)mb * 128) * 64;
    const u8* slabW = Wd8 + (size_t)t * 48 * 64;
#pragma unroll
    for (int p = 0; p < 2; ++p)
      gload_lds16(slabA + (p * 4 + wave) * 1024 + sgoff8, lsA + (p * 4 + wave) * 1024);
    if (wave < 3)
      gload_lds16(slabW + wave * 1024 + sgoff8, lsW + wave * 1024);
    asm volatile("s_waitcnt vmcnt(0)" ::: "memory");
    __syncthreads();

    lng2 wf[3], af[2];
#pragma unroll
    for (int f = 0; f < 3; ++f)
      wf[f] = *(const lng2*)(lsW + (f * 16 + r16) * 64 + kx);
#pragma unroll
    for (int g = 0; g < 2; ++g)
      af[g] = *(const lng2*)(lsA + (wave * 32 + g * 16 + r16) * 64 + kx);
#pragma unroll
    for (int f = 0; f < 3; ++f)
#pragma unroll
      for (int g = 0; g < 2; ++g) {
        acc[f][g] = __builtin_amdgcn_mfma_f32_16x16x32_fp8_fp8(wf[f][0], af[g][0], acc[f][g], 0, 0, 0);
        acc[f][g] = __builtin_amdgcn_mfma_f32_16x16x32_fp8_fp8(wf[f][1], af[g][1], acc[f][g], 0, 0, 0);
      }
    __syncthreads();
  }

  const int rg = lane >> 4;
#pragma unroll
  for (int f = 0; f < 3; ++f)
#pragma unroll
    for (int r = 0; r < 4; ++r)
#pragma unroll
      for (int g = 0; g < 2; ++g)
        trn[wave * 32 + g * 16 + r16][f * 16 + rg * 4 + r] = acc[f][g][r] * 0.0625f;
  __syncthreads();

  if (tid < 128) {
    float gv[48];
#pragma unroll
    for (int j = 0; j < 48; ++j) gv[j] = trn[tid][j];
    float f0[16], f1[16], f2[16];
#pragma unroll
    for (int j = 0; j < 16; ++j) f0[j] = lrelu(gv[j] + biases[j]);
#pragma unroll
    for (int j = 0; j < 16; ++j) {
      float a = gv[16 + j] + biases[16 + j];
#pragma unroll
      for (int i = 0; i < 16; ++i) a += f0[i] * w1t[i][j];
      f1[j] = lrelu(a);
    }
#pragma unroll
    for (int j = 0; j < 16; ++j) {
      float a = gv[32 + j] + biases[32 + j];
#pragma unroll
      for (int i = 0; i < 16; ++i) a += f0[i] * w2t[i][j];
#pragma unroll
      for (int i = 0; i < 16; ++i) a += f1[i] * w2t[16 + i][j];
      f2[j] = lrelu(a);
    }
    u8* dst = A8out + ((size_t)32 * HW_N + mb * 128 + tid) * 64;
#pragma unroll
    for (int c = 0; c < 4; ++c) {
      u8x16 y;
#pragma unroll
      for (int w = 0; w < 16; ++w) {
        const int k = (w < 8) ? (c * 8 + w) : (32 + c * 8 + (w - 8));
        const float v = (k < 16) ? f0[k] : (k < 32) ? f1[k - 16] : (k < 48) ? f2[k - 32] : 0.0f;
        y[w] = f2fp8(v);
      }
      *(u8x16*)(dst + c * 16) = y;
    }
  }
}

// ---------------- kernel 4: tiny z-axis attention ----------------
__global__ __launch_bounds__(256) void k_attn(const float* __restrict__ pooled_sum,
    const float* __restrict__ ln_w, const float* __restrict__ ln_b,
    const float* __restrict__ wq, const float* __restrict__ bq,
    const float* __restrict__ wk, const float* __restrict__ bk,
    const float* __restrict__ wv, const float* __restrict__ bv,
    const float* __restrict__ wo, const float* __restrict__ bo,
    const float* __restrict__ relz, const float* __restrict__ attn_gamma,
    float* __restrict__ o_scaled) {
  __shared__ float pooled[2048];
  __shared__ float q[512], k[512], v[512], att[4096], tz[512];
  const int tid = threadIdx.x;
  for (int i = tid; i < 2048; i += 256) {
    int c = i & 63;
    pooled[i] = ln_w[c] * pooled_sum[i] * (1.0f / 16384.0f) + ln_b[c];
  }
  __syncthreads();
  for (int i = tid; i < 512; i += 256) {
    int z = i >> 4, e = i & 15;
    float aq = bq[e], ak = bk[e], av = bv[e];
    for (int c = 0; c < 64; ++c) {
      float p = pooled[z * 64 + c];
      aq += p * wq[c * 16 + e]; ak += p * wk[c * 16 + e]; av += p * wv[c * 16 + e];
    }
    q[i] = aq; k[i] = ak; v[i] = av;
  }
  __syncthreads();
  if (tid < 128) {
    int h = tid >> 5, zi = tid & 31;
    float s[32]; float mx = -1e30f;
#pragma unroll
    for (int j = 0; j < 32; ++j) {
      float d = 0.f;
#pragma unroll
      for (int e = 0; e < 4; ++e) d += q[zi * 16 + h * 4 + e] * k[j * 16 + h * 4 + e];
      d = d * 0.5f + relz[h * 65 + (j - zi + 32)];
      s[j] = d; mx = fmaxf(mx, d);
    }
    float ssum = 0.f;
#pragma unroll
    for (int j = 0; j < 32; ++j) { s[j] = __expf(s[j] - mx); ssum += s[j]; }
    float inv = 1.0f / ssum;
#pragma unroll
    for (int j = 0; j < 32; ++j) att[(h * 32 + zi) * 32 + j] = s[j] * inv;
  }
  __syncthreads();
  for (int i = tid; i < 512; i += 256) {
    int z = i >> 4, hd = i & 15, h = hd >> 2;
    float a = 0.f;
    for (int j = 0; j < 32; ++j) a += att[(h * 32 + z) * 32 + j] * v[j * 16 + hd];
    tz[i] = a;
  }
  __syncthreads();
  const float gamma = attn_gamma[0];
  for (int i = tid; i < 2048; i += 256) {
    int z = i >> 6, c = i & 63;
    float a = bo[c];
    for (int hd = 0; hd < 16; ++hd) a += tz[z * 16 + hd] * wo[hd * 64 + c];
    o_scaled[i] = gamma * a;
  }
}

// ---------------- kernel 5: main GEMM, fp8 K=32, BM=128 x BN=256, 4-wave, 3 blocks/CU --------
// 48 KB LDS (2 buf x (A 8K + W 16K)) -> 3 blocks/CU = 3 waves/SIMD (was 2): more TLP to hide
// the per-tile stage drain. Quadrant pipeline: prefetch (cf03, pf) across tile boundary;
// stages A@Q1, W@Q2; one vmcnt(0)+barrier @Q4. Wave tile = 64 pix x 128 ch.
__global__ __launch_bounds__(256, 3) void k_gemm(
    const u8* __restrict__ A8, const u8* __restrict__ W8,
    const float* __restrict__ trans, const float* __restrict__ o_scaled,
    const float* __restrict__ fuse_b, const float* __restrict__ rdc_scale,
    float* __restrict__ out) {
  __shared__ __align__(16) u8 ls[49152];  // 48 KB
  const int tid = threadIdx.x;
  const int lane = tid & 63;
  const int wave = __builtin_amdgcn_readfirstlane(tid >> 6);  // 0..3
  const int bid = blockIdx.x;
  const int nb = bid & 7;        // XCD owns one 256-ch W panel (L2-resident)
  const int mb = bid >> 3;       // 128 m-tiles of 128 pixels
  const int mbase = mb * 128, nbase = nb * 256;
  const int wm = wave & 1;       // 64-pixel half
  const int wn = wave >> 1;      // 128-channel half
  const int prow = wm * 64;
  const int crow = wn * 128;
  const int r16 = lane & 15, kgrp = lane >> 4;
  const int sgoff8 = ((lane >> 2) << 6) + (((lane & 3) ^ ((lane >> 3) & 3)) << 4);
  const int kx = (kgrp ^ ((r16 >> 1) & 3)) << 4;

#define LA(b) (ls + (b) * 24576)
#define LW(b) (ls + (b) * 24576 + 8192)
#define ATILE(t) (A8 + ((size_t)(t) * HW_N + mbase) * 64)
#define WTILE(t) (W8 + ((size_t)(t) * NCH + nbase) * 64)
#define STA(t, b)                                                              \
  do {                                                                         \
    gload_lds16(ATILE(t) + wave * 1024 + sgoff8, LA(b) + wave * 1024);         \
    gload_lds16(ATILE(t) + 4096 + wave * 1024 + sgoff8, LA(b) + 4096 + wave * 1024); \
  } while (0)
#define STW(t, b)                                                              \
  do {                                                                         \
    _Pragma("unroll") for (int i_ = 0; i_ < 4; ++i_)                           \
      gload_lds16(WTILE(t) + (i_ * 4 + wave) * 1024 + sgoff8,                  \
                  LW(b) + (i_ * 4 + wave) * 1024);                             \
  } while (0)
#define RD8(base, row) (*(const lng2*)((base) + (row) * 64 + kx))
#define MF8(a, b, c) __builtin_amdgcn_mfma_f32_16x16x32_fp8_fp8((a), (b), (c), 0, 0, 0)

  f32x4 acc[8][4] = {};   // [f: 8 ch-frags][g: 4 pix-frags]
  lng2 cfa[4], pfa[4];    // prefetched set A: cf f0..3 + pf all
  lng2 cfb[4], pfb[4];    // set B

  // ---- prologue: stage tile 0; read (cf03, pf)(0) ----
  STA(0, 0);
  STW(0, 0);
  asm volatile("s_waitcnt vmcnt(0)" ::: "memory");
  __builtin_amdgcn_s_barrier();
#pragma unroll
  for (int f = 0; f < 4; ++f) cfa[f] = RD8(LW(0), crow + f * 16 + r16);
#pragma unroll
  for (int g = 0; g < 4; ++g) pfa[g] = RD8(LA(0), prow + g * 16 + r16);

#define GBODY(T, CFC, PFC, CFN, PFN)                                           \
  {                                                                            \
    const int t = (T);                                                         \
    const int buf = t & 1, nbf = buf ^ 1;                                      \
    const int tn = (t + 1 < 33) ? t + 1 : 32;                                  \
    lng2 cf47[4];                                                              \
    /* Q1: read cf47(t); stage A(t+1); MFMA f0-1 x g */                        \
    _Pragma("unroll") for (int f = 0; f < 4; ++f)                              \
      cf47[f] = RD8(LW(buf), crow + 64 + f * 16 + r16);                        \
    STA(tn, nbf);                                                              \
    __builtin_amdgcn_s_setprio(1);                                             \
    _Pragma("unroll") for (int f = 0; f < 2; ++f)                              \
      _Pragma("unroll") for (int g = 0; g < 4; ++g) {                          \
        acc[f][g] = MF8(CFC[f][0], PFC[g][0], acc[f][g]);                      \
        acc[f][g] = MF8(CFC[f][1], PFC[g][1], acc[f][g]);                      \
      }                                                                        \
    __builtin_amdgcn_s_setprio(0);                                             \
    /* Q2: stage W(t+1); MFMA f2-3 x g */                                      \
    STW(tn, nbf);                                                              \
    __builtin_amdgcn_s_setprio(1);                                             \
    _Pragma("unroll") for (int f = 0; f < 2; ++f)                              \
      _Pragma("unroll") for (int g = 0; g < 4; ++g) {                          \
        acc[2 + f][g] = MF8(CFC[2 + f][0], PFC[g][0], acc[2 + f][g]);          \
        acc[2 + f][g] = MF8(CFC[2 + f][1], PFC[g][1], acc[2 + f][g]);          \
      }                                                                        \
    __builtin_amdgcn_s_setprio(0);                                             \
    /* Q3: MFMA f4-5 x g (no reads) */                                         \
    __builtin_amdgcn_s_setprio(1);                                             \
    _Pragma("unroll") for (int f = 0; f < 2; ++f)                              \
      _Pragma("unroll") for (int g = 0; g < 4; ++g) {                          \
        acc[4 + f][g] = MF8(cf47[f][0], PFC[g][0], acc[4 + f][g]);             \
        acc[4 + f][g] = MF8(cf47[f][1], PFC[g][1], acc[4 + f][g]);             \
      }                                                                        \
    __builtin_amdgcn_s_setprio(0);                                             \
    /* Q4: vmcnt drain; barrier; read (cf03, pf)(t+1); MFMA f6-7 x g */        \
    asm volatile("s_waitcnt vmcnt(0)" ::: "memory");                           \
    __builtin_amdgcn_s_barrier();                                              \
    _Pragma("unroll") for (int f = 0; f < 4; ++f)                              \
      CFN[f] = RD8(LW(nbf), crow + f * 16 + r16);                              \
    _Pragma("unroll") for (int g = 0; g < 4; ++g)                              \
      PFN[g] = RD8(LA(nbf), prow + g * 16 + r16);                              \
    __builtin_amdgcn_s_setprio(1);                                             \
    _Pragma("unroll") for (int f = 0; f < 2; ++f)                              \
      _Pragma("unroll") for (int g = 0; g < 4; ++g) {                          \
        acc[6 + f][g] = MF8(cf47[2 + f][0], PFC[g][0], acc[6 + f][g]);         \
        acc[6 + f][g] = MF8(cf47[2 + f][1], PFC[g][1], acc[6 + f][g]);         \
      }                                                                        \
    __builtin_amdgcn_s_setprio(0);                                             \
  }

  for (int u = 0; u < 16; ++u) {
    GBODY(2 * u, cfa, pfa, cfb, pfb);
    GBODY(2 * u + 1, cfb, pfb, cfa, pfa);
  }
  GBODY(32, cfa, pfa, cfb, pfb);

  asm volatile("s_waitcnt vmcnt(0)" ::: "memory");

  // epilogue: out = trans + rdc*lrelu(acc/16 + fuse_b) + o_scaled   (/16 undoes W scale)
  const float rdc = rdc_scale[0];
  const int rg = lane >> 4;
#pragma unroll
  for (int f = 0; f < 8; ++f) {
#pragma unroll
    for (int r = 0; r < 4; ++r) {
      const int row = nbase + crow + f * 16 + rg * 4 + r;   // channel
      const float ob = o_scaled[row], fb = fuse_b[row];
#pragma unroll
      for (int g = 0; g < 4; ++g) {
        const int col = mbase + prow + g * 16 + r16;        // pixel
        float v = lrelu(acc[f][g][r] * 0.0625f + fb);
        const size_t idx = (size_t)row * HW_N + col;
        out[idx] = trans[idx] + rdc * v + ob;
      }
    }
  }
#undef GBODY
#undef LA
#undef LW
#undef ATILE
#undef WTILE
#undef STA
#undef STW
#undef RD8
#undef MF8
}

extern "C" void kernel_launch(void* const* d_in, const int* in_sizes, int n_in,
                              void* d_out, int out_size, void* d_ws, size_t ws_size,
                              hipStream_t stream) {
  (void)in_sizes; (void)n_in; (void)out_size; (void)ws_size;
  const float* trans = (const float*)d_in[0];
  const float* ln_w  = (const float*)d_in[1];
  const float* ln_b  = (const float*)d_in[2];
  const float* wq = (const float*)d_in[3];  const float* bq = (const float*)d_in[4];
  const float* wk = (const float*)d_in[5];  const float* bk = (const float*)d_in[6];
  const float* wv = (const float*)d_in[7];  const float* bv = (const float*)d_in[8];
  const float* wo = (const float*)d_in[9];  const float* bo = (const float*)d_in[10];
  const float* relz  = (const float*)d_in[11];
  const float* gamma = (const float*)d_in[12];
  const float* dw0 = (const float*)d_in[13]; const float* db0 = (const float*)d_in[14];
  const float* dw1 = (const float*)d_in[15]; const float* db1 = (const float*)d_in[16];
  const float* dw2 = (const float*)d_in[17]; const float* db2 = (const float*)d_in[18];
  const float* fuse_w = (const float*)d_in[19];
  const float* fuse_b = (const float*)d_in[20];
  const float* rdc    = (const float*)d_in[21];
  float* out = (float*)d_out;

  char* ws = (char*)d_ws;
  u8*    A8         = (u8*)ws;                       // 33*16384*64 = 34,603,008 B
  u8*    W8         = (u8*)(ws + 34603008);          // 33*2048*64  =  4,325,376 B
  u8*    Wd8        = (u8*)(ws + 38928384);          // 32*48*64    =     98,304 B
  float* pooled_sum = (float*)(ws + 39026688);       // 8 KB
  float* o_scaled   = (float*)(ws + 39034880);       // 8 KB

  hipMemsetAsync(pooled_sum, 0, 2048 * sizeof(float), stream);
  k_stats<<<dim3(32, 64), 256, 0, stream>>>(trans, A8, pooled_sum);
  k_wpack<<<dim3(33, 33), 256, 0, stream>>>(fuse_w, dw0, dw1, dw2, W8, Wd8);
  k_dense<<<dim3(128), 256, 0, stream>>>(A8, Wd8, dw1, dw2, db0, db1, db2, A8);
  k_attn<<<dim3(1), 256, 0, stream>>>(pooled_sum, ln_w, ln_b, wq, bq, wk, bk, wv, bv,
                                      wo, bo, relz, gamma, o_scaled);
  k_gemm<<<dim3(1024), 256, 0, stream>>>(A8, W8, trans, o_scaled, fuse_b, rdc, out);
}

// Round 15
// 206.396 us; speedup vs baseline: 2.9580x; 2.9580x over previous
//
#include <hip/hip_runtime.h>
#include <hip/hip_fp8.h>

typedef unsigned char u8;
typedef unsigned short u16;
typedef long lng2 __attribute__((ext_vector_type(2)));
typedef float f32x4 __attribute__((ext_vector_type(4)));
typedef u16 u16x8 __attribute__((ext_vector_type(8)));
typedef u8 u8x16 __attribute__((ext_vector_type(16)));

#define HW_N 16384   // 128*128 pixels
#define NCH  2048
// A8 layout: [kc 0..32][pixel 16384][64 bytes]  fp8 e4m3, k-interleaved:
//   byte b holds k = (b&15)<8 ? (b>>4)*8+(b&7) : 32+(b>>4)*8+(b&7)
// W8 layout: [kc][ch 2048][64 bytes], same permutation, values pre-scaled x16
// Wd8 layout: [kc 0..31][j 48][64 bytes], x16
// LDS swizzle (k_gemm/k_dense): LDS[row][c] = global[row][c ^ ((row>>1)&3)]
//   (write via pre-swizzled gload source; read chunk = kgrp ^ ((r16>>1)&3))

__device__ __forceinline__ u16 f2bf(float f) {
  union { float f; unsigned u; } v; v.f = f;
  unsigned r = v.u + 0x7FFFu + ((v.u >> 16) & 1u);
  return (u16)(r >> 16);
}
__device__ __forceinline__ float bf2f(u16 u) {
  union { unsigned u; float f; } v; v.u = ((unsigned)u) << 16; return v.f;
}
__device__ __forceinline__ u8 f2fp8(float f) {
  __hip_fp8_e4m3 t(f);
  return (u8)t.__x;
}
__device__ __forceinline__ float lrelu(float v) { return v >= 0.0f ? v : 0.2f * v; }

__device__ __forceinline__ void gload_lds16(const u8* g, u8* l) {
  __builtin_amdgcn_global_load_lds((const __attribute__((address_space(1))) void*)g,
                                   (__attribute__((address_space(3))) void*)l, 16, 0, 0);
}

// ---------------- kernel 1: LN stats + pooled partial + coalesced fp8 A copy ----------------
__global__ __launch_bounds__(256) void k_stats(const float* __restrict__ trans,
                                               u8* __restrict__ A8,
                                               float* __restrict__ pooled_sum) {
  const int z = blockIdx.x;
  const int tid = threadIdx.x;
  const int ptile = blockIdx.y;
  const int p = ptile * 256 + tid;
  const float* src = trans + (size_t)z * 64 * HW_N + p;
  float x[64];
#pragma unroll
  for (int c = 0; c < 64; ++c) x[c] = src[(size_t)c * HW_N];
  float sum = 0.f, sq = 0.f;
#pragma unroll
  for (int c = 0; c < 64; ++c) { sum += x[c]; sq += x[c] * x[c]; }
  const float mu = sum * (1.0f / 64.0f);
  const float var = sq * (1.0f / 64.0f) - mu * mu;
  const float rstd = rsqrtf(var + 1e-5f);

  __shared__ __align__(16) u8 rawt[256 * 64];    // 16 KB fp8 (permuted)
  __shared__ __align__(16) u16 normt[256 * 64];  // 32 KB bf16 (pooling path)
  const int r3m = tid & 3, r7 = tid & 7;
#pragma unroll
  for (int c = 0; c < 4; ++c) {
    u8x16 y;
#pragma unroll
    for (int w = 0; w < 16; ++w) {
      const int k = (w < 8) ? (c * 8 + w) : (32 + c * 8 + (w - 8));
      y[w] = f2fp8(x[k]);
    }
    *(u8x16*)&rawt[tid * 64 + ((c ^ r3m) << 4)] = y;
  }
#pragma unroll
  for (int c8 = 0; c8 < 8; ++c8) {
    u16x8 wn;
#pragma unroll
    for (int e = 0; e < 8; ++e) wn[e] = f2bf((x[c8 * 8 + e] - mu) * rstd);
    *(u16x8*)&normt[tid * 64 + ((c8 ^ r7) << 3)] = wn;
  }
  __syncthreads();

  // coalesced writeout of 16 KB fp8 tile (global stays canonical-interleaved)
  u8* gbase = A8 + ((size_t)z * HW_N + (size_t)ptile * 256) * 64;
#pragma unroll
  for (int it = 0; it < 4; ++it) {
    const int o = it * 256 + tid;
    const int row = o >> 2, c4 = o & 3;
    *(u8x16*)(gbase + o * 16) = *(const u8x16*)&rawt[row * 64 + ((c4 ^ (row & 3)) << 4)];
  }

  // pooled[z][c] partial from norm tile
  const int c = tid & 63, q = tid >> 6;
  const int kc2 = c >> 3, e2 = c & 7;
  float s = 0.f;
#pragma unroll 8
  for (int i = 0; i < 64; ++i) {
    const int row = q * 64 + i;
    s += bf2f(normt[row * 64 + ((kc2 ^ (row & 7)) << 3) + e2]);
  }
  __shared__ float red2[4][64];
  red2[q][c] = s;
  __syncthreads();
  if (tid < 64) {
    atomicAdd(&pooled_sum[z * 64 + tid],
              red2[0][tid] + red2[1][tid] + red2[2][tid] + red2[3][tid]);
  }
}

// ---------------- kernel 2: pack fuse_w -> W8 AND dense weights -> Wd8 (one dispatch) --------
// grid (33, 33): blockIdx.y < 32 -> W8 tile (ktile, ntile); blockIdx.y == 32 -> Wd8 (kc=ktile<32).
__global__ __launch_bounds__(256) void k_wpack(const float* __restrict__ fw,
                                               const float* __restrict__ dw0,
                                               const float* __restrict__ dw1,
                                               const float* __restrict__ dw2,
                                               u8* __restrict__ W8,
                                               u8* __restrict__ Wd8) {
  __shared__ float tile[64][65];
  const int tid = threadIdx.x;
  const int ktile = blockIdx.x;
  const int yb = blockIdx.y;
  if (yb == 32) {
    // ---- Wd8 pack (x16, interleaved pos) ----
    const int kc = ktile;
    if (kc >= 32) return;
    for (int idx = tid; idx < 3072; idx += 256) {
      const int kk = idx / 48, j = idx % 48;
      const int k = kc * 64 + kk;
      float v = (j < 16) ? dw0[k * 16 + j]
              : (j < 32) ? dw1[k * 16 + (j - 16)]
                         : dw2[k * 16 + (j - 32)];
      tile[kk][j] = v;
    }
    __syncthreads();
    for (int idx = tid; idx < 3072; idx += 256) {
      const int j = idx / 64, kk = idx % 64;
      const int pos = ((kk >> 3) & 3) * 16 + (kk & 7) + ((kk >> 5) << 3);
      Wd8[((size_t)kc * 48 + j) * 64 + pos] = f2fp8(16.0f * tile[kk][j]);
    }
    return;
  }
  // ---- W8 pack: fuse_w [K][N] fp32 -> [kc][n][64B] fp8 (x16, interleaved pos) ----
  const int ntile = yb;
  {
    const int kk0 = tid >> 6, nn = tid & 63;
#pragma unroll
    for (int it = 0; it < 16; ++it) {
      int kk = it * 4 + kk0;
      int kg = ktile * 64 + kk;
      tile[kk][nn] = (kg < 2096) ? fw[(size_t)kg * NCH + ntile * 64 + nn] : 0.0f;
    }
  }
  __syncthreads();
  {
    const int kk = tid & 63, nn0 = tid >> 6;
    const int pos = ((kk >> 3) & 3) * 16 + (kk & 7) + ((kk >> 5) << 3);
#pragma unroll
    for (int it = 0; it < 16; ++it) {
      int n = it * 4 + nn0;
      W8[((size_t)ktile * NCH + ntile * 64 + n) * 64 + pos] = f2fp8(16.0f * tile[kk][n]);
    }
  }
}

// ---------------- kernel 3: dense chain, fused: GEMM(full K) + f0/f1/f2 + pack slab 32 --------
// grid 128 x 256 thr. Per block: 128 pixels, K=2048 in 32 staged steps (r10 MFMA pattern),
// then acc -> LDS transpose -> per-pixel chain -> A8 slab 32 (interleaved bytes).
__global__ __launch_bounds__(256) void k_dense(const u8* __restrict__ A8,
    const u8* __restrict__ Wd8,
    const float* __restrict__ dw1, const float* __restrict__ dw2,
    const float* __restrict__ db0, const float* __restrict__ db1,
    const float* __restrict__ db2, u8* __restrict__ A8out) {
  __shared__ __align__(16) u8 lsA[128 * 64];  // 8 KB
  __shared__ __align__(16) u8 lsW[48 * 64];   // 3 KB
  __shared__ float trn[128][49];              // 24.5 KB
  __shared__ float w1t[16][16];
  __shared__ float w2t[32][16];
  __shared__ float biases[48];
  const int tid = threadIdx.x;
  const int lane = tid & 63;
  const int wave = __builtin_amdgcn_readfirstlane(tid >> 6);
  const int mb = blockIdx.x;
  const int r16 = lane & 15, kgrp = lane >> 4;
  const int sgoff8 = ((lane >> 2) << 6) + (((lane & 3) ^ ((lane >> 3) & 3)) << 4);
  const int kx = (kgrp ^ ((r16 >> 1) & 3)) << 4;

  if (tid < 256) w1t[tid >> 4][tid & 15] = dw1[(2048 + (tid >> 4)) * 16 + (tid & 15)];
  for (int idx = tid; idx < 512; idx += 256)
    w2t[idx >> 4][idx & 15] = dw2[(2048 + (idx >> 4)) * 16 + (idx & 15)];
  if (tid < 48) biases[tid] = (tid < 16) ? db0[tid] : (tid < 32) ? db1[tid - 16] : db2[tid - 32];

  f32x4 acc[3][2] = {};
  for (int t = 0; t < 32; ++t) {
    const u8* slabA = A8 + ((size_t)t * HW_N + (size_t)mb * 128) * 64;
    const u8* slabW = Wd8 + (size_t)t * 48 * 64;
#pragma unroll
    for (int p = 0; p < 2; ++p)
      gload_lds16(slabA + (p * 4 + wave) * 1024 + sgoff8, lsA + (p * 4 + wave) * 1024);
    if (wave < 3)
      gload_lds16(slabW + wave * 1024 + sgoff8, lsW + wave * 1024);
    asm volatile("s_waitcnt vmcnt(0)" ::: "memory");
    __syncthreads();

    lng2 wf[3], af[2];
#pragma unroll
    for (int f = 0; f < 3; ++f)
      wf[f] = *(const lng2*)(lsW + (f * 16 + r16) * 64 + kx);
#pragma unroll
    for (int g = 0; g < 2; ++g)
      af[g] = *(const lng2*)(lsA + (wave * 32 + g * 16 + r16) * 64 + kx);
#pragma unroll
    for (int f = 0; f < 3; ++f)
#pragma unroll
      for (int g = 0; g < 2; ++g) {
        acc[f][g] = __builtin_amdgcn_mfma_f32_16x16x32_fp8_fp8(wf[f][0], af[g][0], acc[f][g], 0, 0, 0);
        acc[f][g] = __builtin_amdgcn_mfma_f32_16x16x32_fp8_fp8(wf[f][1], af[g][1], acc[f][g], 0, 0, 0);
      }
    __syncthreads();
  }

  // acc -> LDS transpose: trn[pixel][j]  (j = f*16 + rg*4 + r, pixel = wave*32 + g*16 + r16)
  const int rg = lane >> 4;
#pragma unroll
  for (int f = 0; f < 3; ++f)
#pragma unroll
    for (int r = 0; r < 4; ++r)
#pragma unroll
      for (int g = 0; g < 2; ++g)
        trn[wave * 32 + g * 16 + r16][f * 16 + rg * 4 + r] = acc[f][g][r] * 0.0625f;
  __syncthreads();

  if (tid < 128) {
    float gv[48];
#pragma unroll
    for (int j = 0; j < 48; ++j) gv[j] = trn[tid][j];
    float f0[16], f1[16], f2[16];
#pragma unroll
    for (int j = 0; j < 16; ++j) f0[j] = lrelu(gv[j] + biases[j]);
#pragma unroll
    for (int j = 0; j < 16; ++j) {
      float a = gv[16 + j] + biases[16 + j];
#pragma unroll
      for (int i = 0; i < 16; ++i) a += f0[i] * w1t[i][j];
      f1[j] = lrelu(a);
    }
#pragma unroll
    for (int j = 0; j < 16; ++j) {
      float a = gv[32 + j] + biases[32 + j];
#pragma unroll
      for (int i = 0; i < 16; ++i) a += f0[i] * w2t[i][j];
#pragma unroll
      for (int i = 0; i < 16; ++i) a += f1[i] * w2t[16 + i][j];
      f2[j] = lrelu(a);
    }
    u8* dst = A8out + ((size_t)32 * HW_N + mb * 128 + tid) * 64;
#pragma unroll
    for (int c = 0; c < 4; ++c) {
      u8x16 y;
#pragma unroll
      for (int w = 0; w < 16; ++w) {
        const int k = (w < 8) ? (c * 8 + w) : (32 + c * 8 + (w - 8));
        const float v = (k < 16) ? f0[k] : (k < 32) ? f1[k - 16] : (k < 48) ? f2[k - 32] : 0.0f;
        y[w] = f2fp8(v);
      }
      *(u8x16*)(dst + c * 16) = y;
    }
  }
}

// ---------------- kernel 4: tiny z-axis attention ----------------
__global__ __launch_bounds__(256) void k_attn(const float* __restrict__ pooled_sum,
    const float* __restrict__ ln_w, const float* __restrict__ ln_b,
    const float* __restrict__ wq, const float* __restrict__ bq,
    const float* __restrict__ wk, const float* __restrict__ bk,
    const float* __restrict__ wv, const float* __restrict__ bv,
    const float* __restrict__ wo, const float* __restrict__ bo,
    const float* __restrict__ relz, const float* __restrict__ attn_gamma,
    float* __restrict__ o_scaled) {
  __shared__ float pooled[2048];
  __shared__ float q[512], k[512], v[512], att[4096], tz[512];
  const int tid = threadIdx.x;
  for (int i = tid; i < 2048; i += 256) {
    int c = i & 63;
    pooled[i] = ln_w[c] * pooled_sum[i] * (1.0f / 16384.0f) + ln_b[c];
  }
  __syncthreads();
  for (int i = tid; i < 512; i += 256) {
    int z = i >> 4, e = i & 15;
    float aq = bq[e], ak = bk[e], av = bv[e];
    for (int c = 0; c < 64; ++c) {
      float p = pooled[z * 64 + c];
      aq += p * wq[c * 16 + e]; ak += p * wk[c * 16 + e]; av += p * wv[c * 16 + e];
    }
    q[i] = aq; k[i] = ak; v[i] = av;
  }
  __syncthreads();
  if (tid < 128) {
    int h = tid >> 5, zi = tid & 31;
    float s[32]; float mx = -1e30f;
#pragma unroll
    for (int j = 0; j < 32; ++j) {
      float d = 0.f;
#pragma unroll
      for (int e = 0; e < 4; ++e) d += q[zi * 16 + h * 4 + e] * k[j * 16 + h * 4 + e];
      d = d * 0.5f + relz[h * 65 + (j - zi + 32)];
      s[j] = d; mx = fmaxf(mx, d);
    }
    float ssum = 0.f;
#pragma unroll
    for (int j = 0; j < 32; ++j) { s[j] = __expf(s[j] - mx); ssum += s[j]; }
    float inv = 1.0f / ssum;
#pragma unroll
    for (int j = 0; j < 32; ++j) att[(h * 32 + zi) * 32 + j] = s[j] * inv;
  }
  __syncthreads();
  for (int i = tid; i < 512; i += 256) {
    int z = i >> 4, hd = i & 15, h = hd >> 2;
    float a = 0.f;
    for (int j = 0; j < 32; ++j) a += att[(h * 32 + z) * 32 + j] * v[j * 16 + hd];
    tz[i] = a;
  }
  __syncthreads();
  const float gamma = attn_gamma[0];
  for (int i = tid; i < 2048; i += 256) {
    int z = i >> 6, c = i & 63;
    float a = bo[c];
    for (int hd = 0; hd < 16; ++hd) a += tz[z * 16 + hd] * wo[hd * 64 + c];
    o_scaled[i] = gamma * a;
  }
}

// ---------------- kernel 5: main GEMM, fp8, 256x256, 8-wave, r5 quadrant pipeline (r10) ------
// LDS 64 KB: 2 buf x (A 16K + W 16K). XOR swizzle (row>>1)&3 -> conflict-free ds_read.
__global__ __launch_bounds__(512, 2) void k_gemm(
    const u8* __restrict__ A8, const u8* __restrict__ W8,
    const float* __restrict__ trans, const float* __restrict__ o_scaled,
    const float* __restrict__ fuse_b, const float* __restrict__ rdc_scale,
    float* __restrict__ out) {
  __shared__ __align__(16) u8 ls[65536];  // 64 KB
  const int tid = threadIdx.x;
  const int lane = tid & 63;
  const int wave = __builtin_amdgcn_readfirstlane(tid >> 6);
  const int bid = blockIdx.x;
  const int nb = bid & 7;        // XCD owns one 256-ch W panel (L2-resident)
  const int mb = bid >> 3;
  const int mbase = mb * 256, nbase = nb * 256;
  const int wm = wave & 1;       // pixel half
  const int wn = wave >> 1;      // channel quarter
  const int wnh = wn >> 1;       // which 128-ch W half
  const int wrow = (wn & 1) * 64;
  const int r16 = lane & 15, kgrp = lane >> 4;
  const int sgoff8 = ((lane >> 2) << 6) + (((lane & 3) ^ ((lane >> 3) & 3)) << 4);
  const int kx = (kgrp ^ ((r16 >> 1) & 3)) << 4;

#define LA(b, h) (ls + (b) * 32768 + (h) * 8192)
#define LW(b, h) (ls + (b) * 32768 + 16384 + (h) * 8192)
#define AHALF(t, h) (A8 + ((size_t)(t) * HW_N + mbase + (h) * 128) * 64)
#define WHALF(t, h) (W8 + ((size_t)(t) * NCH + nbase + (h) * 128) * 64)
#define STAGE(rows, ldsh) gload_lds16((rows) + wave * 1024 + sgoff8, (ldsh) + wave * 1024)
#define RD8(base, row) (*(const lng2*)((base) + (row) * 64 + kx))
#define MF8(a, b, c) __builtin_amdgcn_mfma_f32_16x16x32_fp8_fp8((a), (b), (c), 0, 0, 0)

  f32x4 acc[4][8] = {};   // [f: 4 ch-frags][g: 8 pix-frags]
  lng2 wf0a[2], afLa[4];  // pipelined (wf0, afL) set A
  lng2 wf0b[2], afLb[4];  // set B

  // ---- prologue: stage tile 0, read its (wf0, afL) ----
  STAGE(WHALF(0, 0), LW(0, 0));
  STAGE(WHALF(0, 1), LW(0, 1));
  STAGE(AHALF(0, 0), LA(0, 0));
  STAGE(AHALF(0, 1), LA(0, 1));
  asm volatile("s_waitcnt vmcnt(0)" ::: "memory");
  __builtin_amdgcn_s_barrier();
  {
    const u8* lw0 = LW(0, wnh);
    const u8* la0 = LA(0, wm);
#pragma unroll
    for (int f = 0; f < 2; ++f) wf0a[f] = RD8(lw0, wrow + f * 16 + r16);
#pragma unroll
    for (int g = 0; g < 4; ++g) afLa[g] = RD8(la0, g * 16 + r16);
  }

#define GBODY(T, W0C, ALC, W0N, ALN)                                           \
  {                                                                            \
    const int t = (T);                                                         \
    const int buf = t & 1, nbf = buf ^ 1;                                      \
    const int tn = (t + 1 < 33) ? t + 1 : 32;                                  \
    const u8* la = LA(buf, wm);                                                \
    const u8* lw = LW(buf, wnh);                                               \
    lng2 wf1[2], afH[4];                                                       \
    /* Q1: read wf1(t); stage W(t+1); MFMA f01 x g03 */                        \
    _Pragma("unroll") for (int f = 0; f < 2; ++f)                              \
      wf1[f] = RD8(lw, wrow + 32 + f * 16 + r16);                              \
    STAGE(WHALF(tn, 0), LW(nbf, 0));                                           \
    STAGE(WHALF(tn, 1), LW(nbf, 1));                                           \
    __builtin_amdgcn_s_setprio(1);                                             \
    _Pragma("unroll") for (int f = 0; f < 2; ++f)                              \
      _Pragma("unroll") for (int g = 0; g < 4; ++g) {                          \
        acc[f][g] = MF8(W0C[f][0], ALC[g][0], acc[f][g]);                      \
        acc[f][g] = MF8(W0C[f][1], ALC[g][1], acc[f][g]);                      \
      }                                                                        \
    __builtin_amdgcn_s_setprio(0);                                             \
    /* Q2: read afH(t); stage A(t+1); MFMA f23 x g03 */                        \
    _Pragma("unroll") for (int g = 0; g < 4; ++g)                              \
      afH[g] = RD8(la, 64 + g * 16 + r16);                                     \
    STAGE(AHALF(tn, 0), LA(nbf, 0));                                           \
    STAGE(AHALF(tn, 1), LA(nbf, 1));                                           \
    __builtin_amdgcn_s_setprio(1);                                             \
    _Pragma("unroll") for (int f = 0; f < 2; ++f)                              \
      _Pragma("unroll") for (int g = 0; g < 4; ++g) {                          \
        acc[2 + f][g] = MF8(wf1[f][0], ALC[g][0], acc[2 + f][g]);              \
        acc[2 + f][g] = MF8(wf1[f][1], ALC[g][1], acc[2 + f][g]);              \
      }                                                                        \
    __builtin_amdgcn_s_setprio(0);                                             \
    /* Q3: MFMA f23 x g47 (no reads) */                                        \
    __builtin_amdgcn_s_setprio(1);                                             \
    _Pragma("unroll") for (int f = 0; f < 2; ++f)                              \
      _Pragma("unroll") for (int g = 0; g < 4; ++g) {                          \
        acc[2 + f][4 + g] = MF8(wf1[f][0], afH[g][0], acc[2 + f][4 + g]);      \
        acc[2 + f][4 + g] = MF8(wf1[f][1], afH[g][1], acc[2 + f][4 + g]);      \
      }                                                                        \
    __builtin_amdgcn_s_setprio(0);                                             \
    /* Q4: vmcnt drain; barrier; read (wf0,afL)(t+1); MFMA f01 x g47 */        \
    asm volatile("s_waitcnt vmcnt(0)" ::: "memory");                           \
    __builtin_amdgcn_s_barrier();                                              \
    {                                                                          \
      const u8* lan = LA(nbf, wm);                                             \
      const u8* lwn = LW(nbf, wnh);                                            \
      _Pragma("unroll") for (int f = 0; f < 2; ++f)                            \
        W0N[f] = RD8(lwn, wrow + f * 16 + r16);                                \
      _Pragma("unroll") for (int g = 0; g < 4; ++g)                            \
        ALN[g] = RD8(lan, g * 16 + r16);                                       \
    }                                                                          \
    __builtin_amdgcn_s_setprio(1);                                             \
    _Pragma("unroll") for (int f = 0; f < 2; ++f)                              \
      _Pragma("unroll") for (int g = 0; g < 4; ++g) {                          \
        acc[f][4 + g] = MF8(W0C[f][0], afH[g][0], acc[f][4 + g]);              \
        acc[f][4 + g] = MF8(W0C[f][1], afH[g][1], acc[f][4 + g]);              \
      }                                                                        \
    __builtin_amdgcn_s_setprio(0);                                             \
  }

  for (int u = 0; u < 16; ++u) {
    GBODY(2 * u, wf0a, afLa, wf0b, afLb);
    GBODY(2 * u + 1, wf0b, afLb, wf0a, afLa);
  }
  GBODY(32, wf0a, afLa, wf0b, afLb);

  asm volatile("s_waitcnt vmcnt(0)" ::: "memory");

  // epilogue: out = trans + rdc*lrelu(acc/16 + fuse_b) + o_scaled   (/16 undoes W scale)
  const float rdc = rdc_scale[0];
  const int rg = lane >> 4;
#pragma unroll
  for (int f = 0; f < 4; ++f) {
#pragma unroll
    for (int r = 0; r < 4; ++r) {
      const int row = nbase + wn * 64 + f * 16 + rg * 4 + r;  // channel
      const float ob = o_scaled[row], fb = fuse_b[row];
#pragma unroll
      for (int g = 0; g < 8; ++g) {
        const int col = mbase + wm * 128 + g * 16 + r16;       // pixel
        float v = lrelu(acc[f][g][r] * 0.0625f + fb);
        const size_t idx = (size_t)row * HW_N + col;
        out[idx] = trans[idx] + rdc * v + ob;
      }
    }
  }
#undef GBODY
#undef LA
#undef LW
#undef AHALF
#undef WHALF
#undef STAGE
#undef RD8
#undef MF8
}

extern "C" void kernel_launch(void* const* d_in, const int* in_sizes, int n_in,
                              void* d_out, int out_size, void* d_ws, size_t ws_size,
                              hipStream_t stream) {
  (void)in_sizes; (void)n_in; (void)out_size; (void)ws_size;
  const float* trans = (const float*)d_in[0];
  const float* ln_w  = (const float*)d_in[1];
  const float* ln_b  = (const float*)d_in[2];
  const float* wq = (const float*)d_in[3];  const float* bq = (const float*)d_in[4];
  const float* wk = (const float*)d_in[5];  const float* bk = (const float*)d_in[6];
  const float* wv = (const float*)d_in[7];  const float* bv = (const float*)d_in[8];
  const float* wo = (const float*)d_in[9];  const float* bo = (const float*)d_in[10];
  const float* relz  = (const float*)d_in[11];
  const float* gamma = (const float*)d_in[12];
  const float* dw0 = (const float*)d_in[13]; const float* db0 = (const float*)d_in[14];
  const float* dw1 = (const float*)d_in[15]; const float* db1 = (const float*)d_in[16];
  const float* dw2 = (const float*)d_in[17]; const float* db2 = (const float*)d_in[18];
  const float* fuse_w = (const float*)d_in[19];
  const float* fuse_b = (const float*)d_in[20];
  const float* rdc    = (const float*)d_in[21];
  float* out = (float*)d_out;

  char* ws = (char*)d_ws;
  u8*    A8         = (u8*)ws;                       // 33*16384*64 = 34,603,008 B
  u8*    W8         = (u8*)(ws + 34603008);          // 33*2048*64  =  4,325,376 B
  u8*    Wd8        = (u8*)(ws + 38928384);          // 32*48*64    =     98,304 B
  float* pooled_sum = (float*)(ws + 39026688);       // 8 KB
  float* o_scaled   = (float*)(ws + 39034880);       // 8 KB

  hipMemsetAsync(pooled_sum, 0, 2048 * sizeof(float), stream);
  k_stats<<<dim3(32, 64), 256, 0, stream>>>(trans, A8, pooled_sum);
  k_wpack<<<dim3(33, 33), 256, 0, stream>>>(fuse_w, dw0, dw1, dw2, W8, Wd8);
  k_dense<<<dim3(128), 256, 0, stream>>>(A8, Wd8, dw1, dw2, db0, db1, db2, A8);
  k_attn<<<dim3(1), 256, 0, stream>>>(pooled_sum, ln_w, ln_b, wq, bq, wk, bk, wv, bv,
                                      wo, bo, relz, gamma, o_scaled);
  k_gemm<<<dim3(512), 512, 0, stream>>>(A8, W8, trans, o_scaled, fuse_b, rdc, out);
}

// Round 16
// 192.747 us; speedup vs baseline: 3.1675x; 1.0708x over previous
//
#include <hip/hip_runtime.h>
#include <hip/hip_fp8.h>

typedef unsigned char u8;
typedef unsigned short u16;
typedef long lng2 __attribute__((ext_vector_type(2)));
typedef float f32x4 __attribute__((ext_vector_type(4)));
typedef u16 u16x8 __attribute__((ext_vector_type(8)));
typedef u8 u8x16 __attribute__((ext_vector_type(16)));

#define HW_N 16384   // 128*128 pixels
#define NCH  2048
// A8 layout: [kc 0..32][pixel 16384][64 bytes]  fp8 e4m3, k-interleaved:
//   byte b holds k = (b&15)<8 ? (b>>4)*8+(b&7) : 32+(b>>4)*8+(b&7)
// W8 layout: [kc][ch 2048][64 bytes], same permutation, values pre-scaled x16
// Wd8 layout: [kc 0..31][j 48][64 bytes], x16
// LDS swizzle (k_gemm/dense): LDS[row][c] = global[row][c ^ ((row>>1)&3)]
//   (write via pre-swizzled gload source; read chunk = kgrp ^ ((r16>>1)&3))

__device__ __forceinline__ u16 f2bf(float f) {
  union { float f; unsigned u; } v; v.f = f;
  unsigned r = v.u + 0x7FFFu + ((v.u >> 16) & 1u);
  return (u16)(r >> 16);
}
__device__ __forceinline__ float bf2f(u16 u) {
  union { unsigned u; float f; } v; v.u = ((unsigned)u) << 16; return v.f;
}
__device__ __forceinline__ u8 f2fp8(float f) {
  __hip_fp8_e4m3 t(f);
  return (u8)t.__x;
}
__device__ __forceinline__ float lrelu(float v) { return v >= 0.0f ? v : 0.2f * v; }

__device__ __forceinline__ void gload_lds16(const u8* g, u8* l) {
  __builtin_amdgcn_global_load_lds((const __attribute__((address_space(1))) void*)g,
                                   (__attribute__((address_space(3))) void*)l, 16, 0, 0);
}

// ---------------- kernel 1: k_prep = {LN stats + fp8 A copy} UNION {weight packing} ----------
// grid 3137: blocks 0..2047 -> stats (z = b>>6, ptile = b&63); 2048..3136 -> wpack (33x33).
__global__ __launch_bounds__(256) void k_prep(const float* __restrict__ trans,
                                              const float* __restrict__ fw,
                                              const float* __restrict__ dw0,
                                              const float* __restrict__ dw1,
                                              const float* __restrict__ dw2,
                                              u8* __restrict__ A8,
                                              float* __restrict__ pooled_sum,
                                              u8* __restrict__ W8,
                                              u8* __restrict__ Wd8) {
  __shared__ __align__(16) char smem[50176];
  const int tid = threadIdx.x;
  const int bid = blockIdx.x;

  if (bid < 2048) {
    // ================= stats branch (body = r12 k_stats) =================
    const int z = bid >> 6;
    const int ptile = bid & 63;
    u8*  rawt  = (u8*)smem;                 // 16 KB fp8 (permuted)
    u16* normt = (u16*)(smem + 16384);      // 32 KB bf16
    float (*red2)[64] = (float(*)[64])(smem + 49152);  // 1 KB

    const int p = ptile * 256 + tid;
    const float* src = trans + (size_t)z * 64 * HW_N + p;
    float x[64];
#pragma unroll
    for (int c = 0; c < 64; ++c) x[c] = src[(size_t)c * HW_N];
    float sum = 0.f, sq = 0.f;
#pragma unroll
    for (int c = 0; c < 64; ++c) { sum += x[c]; sq += x[c] * x[c]; }
    const float mu = sum * (1.0f / 64.0f);
    const float var = sq * (1.0f / 64.0f) - mu * mu;
    const float rstd = rsqrtf(var + 1e-5f);

    const int r3m = tid & 3, r7 = tid & 7;
#pragma unroll
    for (int c = 0; c < 4; ++c) {
      u8x16 y;
#pragma unroll
      for (int w = 0; w < 16; ++w) {
        const int k = (w < 8) ? (c * 8 + w) : (32 + c * 8 + (w - 8));
        y[w] = f2fp8(x[k]);
      }
      *(u8x16*)&rawt[tid * 64 + ((c ^ r3m) << 4)] = y;
    }
#pragma unroll
    for (int c8 = 0; c8 < 8; ++c8) {
      u16x8 wn;
#pragma unroll
      for (int e = 0; e < 8; ++e) wn[e] = f2bf((x[c8 * 8 + e] - mu) * rstd);
      *(u16x8*)&normt[tid * 64 + ((c8 ^ r7) << 3)] = wn;
    }
    __syncthreads();

    u8* gbase = A8 + ((size_t)z * HW_N + (size_t)ptile * 256) * 64;
#pragma unroll
    for (int it = 0; it < 4; ++it) {
      const int o = it * 256 + tid;
      const int row = o >> 2, c4 = o & 3;
      *(u8x16*)(gbase + o * 16) = *(const u8x16*)&rawt[row * 64 + ((c4 ^ (row & 3)) << 4)];
    }

    const int c = tid & 63, q = tid >> 6;
    const int kc2 = c >> 3, e2 = c & 7;
    float s = 0.f;
#pragma unroll 8
    for (int i = 0; i < 64; ++i) {
      const int row = q * 64 + i;
      s += bf2f(normt[row * 64 + ((kc2 ^ (row & 7)) << 3) + e2]);
    }
    red2[q][c] = s;
    __syncthreads();
    if (tid < 64) {
      atomicAdd(&pooled_sum[z * 64 + tid],
                red2[0][tid] + red2[1][tid] + red2[2][tid] + red2[3][tid]);
    }
    return;
  }

  // ================= wpack branch (body = r12 k_wpack) =================
  const int idx = bid - 2048;
  const int ktile = idx % 33;
  const int yb = idx / 33;
  float (*tile)[65] = (float(*)[65])smem;   // 16.6 KB

  if (yb == 32) {
    const int kc = ktile;
    if (kc >= 32) return;
    for (int i2 = tid; i2 < 3072; i2 += 256) {
      const int kk = i2 / 48, j = i2 % 48;
      const int k = kc * 64 + kk;
      float v = (j < 16) ? dw0[k * 16 + j]
              : (j < 32) ? dw1[k * 16 + (j - 16)]
                         : dw2[k * 16 + (j - 32)];
      tile[kk][j] = v;
    }
    __syncthreads();
    for (int i2 = tid; i2 < 3072; i2 += 256) {
      const int j = i2 / 64, kk = i2 % 64;
      const int pos = ((kk >> 3) & 3) * 16 + (kk & 7) + ((kk >> 5) << 3);
      Wd8[((size_t)kc * 48 + j) * 64 + pos] = f2fp8(16.0f * tile[kk][j]);
    }
    return;
  }
  const int ntile = yb;
  {
    const int kk0 = tid >> 6, nn = tid & 63;
#pragma unroll
    for (int it = 0; it < 16; ++it) {
      int kk = it * 4 + kk0;
      int kg = ktile * 64 + kk;
      tile[kk][nn] = (kg < 2096) ? fw[(size_t)kg * NCH + ntile * 64 + nn] : 0.0f;
    }
  }
  __syncthreads();
  {
    const int kk = tid & 63, nn0 = tid >> 6;
    const int pos = ((kk >> 3) & 3) * 16 + (kk & 7) + ((kk >> 5) << 3);
#pragma unroll
    for (int it = 0; it < 16; ++it) {
      int n = it * 4 + nn0;
      W8[((size_t)ktile * NCH + ntile * 64 + n) * 64 + pos] = f2fp8(16.0f * tile[kk][n]);
    }
  }
}

// ---------------- kernel 2: k_dattn = {dense chain fused} UNION {tiny attention} -------------
// grid 129: blocks 0..127 -> dense (mb = bid); block 128 -> attention.
__global__ __launch_bounds__(256) void k_dattn(const u8* __restrict__ A8in,
    const u8* __restrict__ Wd8,
    const float* __restrict__ dw1, const float* __restrict__ dw2,
    const float* __restrict__ db0, const float* __restrict__ db1,
    const float* __restrict__ db2, u8* __restrict__ A8out,
    const float* __restrict__ pooled_sum,
    const float* __restrict__ ln_w, const float* __restrict__ ln_b,
    const float* __restrict__ wq, const float* __restrict__ bq,
    const float* __restrict__ wk, const float* __restrict__ bk,
    const float* __restrict__ wv, const float* __restrict__ bv,
    const float* __restrict__ wo, const float* __restrict__ bo,
    const float* __restrict__ relz, const float* __restrict__ attn_gamma,
    float* __restrict__ o_scaled) {
  __shared__ __align__(16) char smem[39680];
  const int tid = threadIdx.x;

  if (blockIdx.x < 128) {
    // ================= dense branch (body = r12 k_dense) =================
    u8* lsA = (u8*)smem;                               // 8 KB
    u8* lsW = (u8*)(smem + 8192);                      // 3 KB
    float (*trn)[49] = (float(*)[49])(smem + 11264);   // 24.5 KB
    float (*w1t)[16] = (float(*)[16])(smem + 36352);   // 1 KB
    float (*w2t)[16] = (float(*)[16])(smem + 37376);   // 2 KB
    float* biases = (float*)(smem + 39424);            // 192 B

    const int lane = tid & 63;
    const int wave = __builtin_amdgcn_readfirstlane(tid >> 6);
    const int mb = blockIdx.x;
    const int r16 = lane & 15, kgrp = lane >> 4;
    const int sgoff8 = ((lane >> 2) << 6) + (((lane & 3) ^ ((lane >> 3) & 3)) << 4);
    const int kx = (kgrp ^ ((r16 >> 1) & 3)) << 4;

    if (tid < 256) w1t[tid >> 4][tid & 15] = dw1[(2048 + (tid >> 4)) * 16 + (tid & 15)];
    for (int i2 = tid; i2 < 512; i2 += 256)
      w2t[i2 >> 4][i2 & 15] = dw2[(2048 + (i2 >> 4)) * 16 + (i2 & 15)];
    if (tid < 48) biases[tid] = (tid < 16) ? db0[tid] : (tid < 32) ? db1[tid - 16] : db2[tid - 32];

    f32x4 acc[3][2] = {};
    for (int t = 0; t < 32; ++t) {
      const u8* slabA = A8in + ((size_t)t * HW_N + (size_t)mb * 128) * 64;
      const u8* slabW = Wd8 + (size_t)t * 48 * 64;
#pragma unroll
      for (int p = 0; p < 2; ++p)
        gload_lds16(slabA + (p * 4 + wave) * 1024 + sgoff8, lsA + (p * 4 + wave) * 1024);
      if (wave < 3)
        gload_lds16(slabW + wave * 1024 + sgoff8, lsW + wave * 1024);
      asm volatile("s_waitcnt vmcnt(0)" ::: "memory");
      __syncthreads();

      lng2 wf[3], af[2];
#pragma unroll
      for (int f = 0; f < 3; ++f)
        wf[f] = *(const lng2*)(lsW + (f * 16 + r16) * 64 + kx);
#pragma unroll
      for (int g = 0; g < 2; ++g)
        af[g] = *(const lng2*)(lsA + (wave * 32 + g * 16 + r16) * 64 + kx);
#pragma unroll
      for (int f = 0; f < 3; ++f)
#pragma unroll
        for (int g = 0; g < 2; ++g) {
          acc[f][g] = __builtin_amdgcn_mfma_f32_16x16x32_fp8_fp8(wf[f][0], af[g][0], acc[f][g], 0, 0, 0);
          acc[f][g] = __builtin_amdgcn_mfma_f32_16x16x32_fp8_fp8(wf[f][1], af[g][1], acc[f][g], 0, 0, 0);
        }
      __syncthreads();
    }

    const int rg = lane >> 4;
#pragma unroll
    for (int f = 0; f < 3; ++f)
#pragma unroll
      for (int r = 0; r < 4; ++r)
#pragma unroll
        for (int g = 0; g < 2; ++g)
          trn[wave * 32 + g * 16 + r16][f * 16 + rg * 4 + r] = acc[f][g][r] * 0.0625f;
    __syncthreads();

    if (tid < 128) {
      float gv[48];
#pragma unroll
      for (int j = 0; j < 48; ++j) gv[j] = trn[tid][j];
      float f0[16], f1[16], f2[16];
#pragma unroll
      for (int j = 0; j < 16; ++j) f0[j] = lrelu(gv[j] + biases[j]);
#pragma unroll
      for (int j = 0; j < 16; ++j) {
        float a = gv[16 + j] + biases[16 + j];
#pragma unroll
        for (int i = 0; i < 16; ++i) a += f0[i] * w1t[i][j];
        f1[j] = lrelu(a);
      }
#pragma unroll
      for (int j = 0; j < 16; ++j) {
        float a = gv[32 + j] + biases[32 + j];
#pragma unroll
        for (int i = 0; i < 16; ++i) a += f0[i] * w2t[i][j];
#pragma unroll
        for (int i = 0; i < 16; ++i) a += f1[i] * w2t[16 + i][j];
        f2[j] = lrelu(a);
      }
      u8* dst = A8out + ((size_t)32 * HW_N + mb * 128 + tid) * 64;
#pragma unroll
      for (int c = 0; c < 4; ++c) {
        u8x16 y;
#pragma unroll
        for (int w = 0; w < 16; ++w) {
          const int k = (w < 8) ? (c * 8 + w) : (32 + c * 8 + (w - 8));
          const float v = (k < 16) ? f0[k] : (k < 32) ? f1[k - 16] : (k < 48) ? f2[k - 32] : 0.0f;
          y[w] = f2fp8(v);
        }
        *(u8x16*)(dst + c * 16) = y;
      }
    }
    return;
  }

  // ================= attention branch (body = r12 k_attn) =================
  float* pooled = (float*)smem;              // 8 KB
  float* qv = (float*)(smem + 8192);         // 2 KB
  float* kv = (float*)(smem + 10240);        // 2 KB
  float* vv = (float*)(smem + 12288);        // 2 KB
  float* att = (float*)(smem + 14336);       // 16 KB
  float* tz = (float*)(smem + 30720);        // 2 KB

  for (int i = tid; i < 2048; i += 256) {
    int c = i & 63;
    pooled[i] = ln_w[c] * pooled_sum[i] * (1.0f / 16384.0f) + ln_b[c];
  }
  __syncthreads();
  for (int i = tid; i < 512; i += 256) {
    int z = i >> 4, e = i & 15;
    float aq = bq[e], ak = bk[e], av = bv[e];
    for (int c = 0; c < 64; ++c) {
      float p = pooled[z * 64 + c];
      aq += p * wq[c * 16 + e]; ak += p * wk[c * 16 + e]; av += p * wv[c * 16 + e];
    }
    qv[i] = aq; kv[i] = ak; vv[i] = av;
  }
  __syncthreads();
  if (tid < 128) {
    int h = tid >> 5, zi = tid & 31;
    float s[32]; float mx = -1e30f;
#pragma unroll
    for (int j = 0; j < 32; ++j) {
      float d = 0.f;
#pragma unroll
      for (int e = 0; e < 4; ++e) d += qv[zi * 16 + h * 4 + e] * kv[j * 16 + h * 4 + e];
      d = d * 0.5f + relz[h * 65 + (j - zi + 32)];
      s[j] = d; mx = fmaxf(mx, d);
    }
    float ssum = 0.f;
#pragma unroll
    for (int j = 0; j < 32; ++j) { s[j] = __expf(s[j] - mx); ssum += s[j]; }
    float inv = 1.0f / ssum;
#pragma unroll
    for (int j = 0; j < 32; ++j) att[(h * 32 + zi) * 32 + j] = s[j] * inv;
  }
  __syncthreads();
  for (int i = tid; i < 512; i += 256) {
    int z = i >> 4, hd = i & 15, h = hd >> 2;
    float a = 0.f;
    for (int j = 0; j < 32; ++j) a += att[(h * 32 + z) * 32 + j] * vv[j * 16 + hd];
    tz[i] = a;
  }
  __syncthreads();
  const float gamma = attn_gamma[0];
  for (int i = tid; i < 2048; i += 256) {
    int z = i >> 6, c = i & 63;
    float a = bo[c];
    for (int hd = 0; hd < 16; ++hd) a += tz[z * 16 + hd] * wo[hd * 64 + c];
    o_scaled[i] = gamma * a;
  }
}

// ---------------- kernel 3: main GEMM, fp8, 256x256, 8-wave, quadrant pipeline (r12) ---------
// LDS 64 KB: 2 buf x (A 16K + W 16K). XOR swizzle (row>>1)&3 -> conflict-free ds_read.
__global__ __launch_bounds__(512, 2) void k_gemm(
    const u8* __restrict__ A8, const u8* __restrict__ W8,
    const float* __restrict__ trans, const float* __restrict__ o_scaled,
    const float* __restrict__ fuse_b, const float* __restrict__ rdc_scale,
    float* __restrict__ out) {
  __shared__ __align__(16) u8 ls[65536];  // 64 KB
  const int tid = threadIdx.x;
  const int lane = tid & 63;
  const int wave = __builtin_amdgcn_readfirstlane(tid >> 6);
  const int bid = blockIdx.x;
  const int nb = bid & 7;        // XCD owns one 256-ch W panel (L2-resident)
  const int mb = bid >> 3;
  const int mbase = mb * 256, nbase = nb * 256;
  const int wm = wave & 1;       // pixel half
  const int wn = wave >> 1;      // channel quarter
  const int wnh = wn >> 1;       // which 128-ch W half
  const int wrow = (wn & 1) * 64;
  const int r16 = lane & 15, kgrp = lane >> 4;
  const int sgoff8 = ((lane >> 2) << 6) + (((lane & 3) ^ ((lane >> 3) & 3)) << 4);
  const int kx = (kgrp ^ ((r16 >> 1) & 3)) << 4;

#define LA(b, h) (ls + (b) * 32768 + (h) * 8192)
#define LW(b, h) (ls + (b) * 32768 + 16384 + (h) * 8192)
#define AHALF(t, h) (A8 + ((size_t)(t) * HW_N + mbase + (h) * 128) * 64)
#define WHALF(t, h) (W8 + ((size_t)(t) * NCH + nbase + (h) * 128) * 64)
#define STAGE(rows, ldsh) gload_lds16((rows) + wave * 1024 + sgoff8, (ldsh) + wave * 1024)
#define RD8(base, row) (*(const lng2*)((base) + (row) * 64 + kx))
#define MF8(a, b, c) __builtin_amdgcn_mfma_f32_16x16x32_fp8_fp8((a), (b), (c), 0, 0, 0)

  f32x4 acc[4][8] = {};   // [f: 4 ch-frags][g: 8 pix-frags]
  lng2 wf0a[2], afLa[4];  // pipelined (wf0, afL) set A
  lng2 wf0b[2], afLb[4];  // set B

  // ---- prologue: stage tile 0, read its (wf0, afL) ----
  STAGE(WHALF(0, 0), LW(0, 0));
  STAGE(WHALF(0, 1), LW(0, 1));
  STAGE(AHALF(0, 0), LA(0, 0));
  STAGE(AHALF(0, 1), LA(0, 1));
  asm volatile("s_waitcnt vmcnt(0)" ::: "memory");
  __builtin_amdgcn_s_barrier();
  {
    const u8* lw0 = LW(0, wnh);
    const u8* la0 = LA(0, wm);
#pragma unroll
    for (int f = 0; f < 2; ++f) wf0a[f] = RD8(lw0, wrow + f * 16 + r16);
#pragma unroll
    for (int g = 0; g < 4; ++g) afLa[g] = RD8(la0, g * 16 + r16);
  }

#define GBODY(T, W0C, ALC, W0N, ALN)                                           \
  {                                                                            \
    const int t = (T);                                                         \
    const int buf = t & 1, nbf = buf ^ 1;                                      \
    const int tn = (t + 1 < 33) ? t + 1 : 32;                                  \
    const u8* la = LA(buf, wm);                                                \
    const u8* lw = LW(buf, wnh);                                               \
    lng2 wf1[2], afH[4];                                                       \
    /* Q1: read wf1(t); stage W(t+1); MFMA f01 x g03 */                        \
    _Pragma("unroll") for (int f = 0; f < 2; ++f)                              \
      wf1[f] = RD8(lw, wrow + 32 + f * 16 + r16);                              \
    STAGE(WHALF(tn, 0), LW(nbf, 0));                                           \
    STAGE(WHALF(tn, 1), LW(nbf, 1));                                           \
    __builtin_amdgcn_s_setprio(1);                                             \
    _Pragma("unroll") for (int f = 0; f < 2; ++f)                              \
      _Pragma("unroll") for (int g = 0; g < 4; ++g) {                          \
        acc[f][g] = MF8(W0C[f][0], ALC[g][0], acc[f][g]);                      \
        acc[f][g] = MF8(W0C[f][1], ALC[g][1], acc[f][g]);                      \
      }                                                                        \
    __builtin_amdgcn_s_setprio(0);                                             \
    /* Q2: read afH(t); stage A(t+1); MFMA f23 x g03 */                        \
    _Pragma("unroll") for (int g = 0; g < 4; ++g)                              \
      afH[g] = RD8(la, 64 + g * 16 + r16);                                     \
    STAGE(AHALF(tn, 0), LA(nbf, 0));                                           \
    STAGE(AHALF(tn, 1), LA(nbf, 1));                                           \
    __builtin_amdgcn_s_setprio(1);                                             \
    _Pragma("unroll") for (int f = 0; f < 2; ++f)                              \
      _Pragma("unroll") for (int g = 0; g < 4; ++g) {                          \
        acc[2 + f][g] = MF8(wf1[f][0], ALC[g][0], acc[2 + f][g]);              \
        acc[2 + f][g] = MF8(wf1[f][1], ALC[g][1], acc[2 + f][g]);              \
      }                                                                        \
    __builtin_amdgcn_s_setprio(0);                                             \
    /* Q3: MFMA f23 x g47 (no reads) */                                        \
    __builtin_amdgcn_s_setprio(1);                                             \
    _Pragma("unroll") for (int f = 0; f < 2; ++f)                              \
      _Pragma("unroll") for (int g = 0; g < 4; ++g) {                          \
        acc[2 + f][4 + g] = MF8(wf1[f][0], afH[g][0], acc[2 + f][4 + g]);      \
        acc[2 + f][4 + g] = MF8(wf1[f][1], afH[g][1], acc[2 + f][4 + g]);      \
      }                                                                        \
    __builtin_amdgcn_s_setprio(0);                                             \
    /* Q4: vmcnt drain; barrier; read (wf0,afL)(t+1); MFMA f01 x g47 */        \
    asm volatile("s_waitcnt vmcnt(0)" ::: "memory");                           \
    __builtin_amdgcn_s_barrier();                                              \
    {                                                                          \
      const u8* lan = LA(nbf, wm);                                             \
      const u8* lwn = LW(nbf, wnh);                                            \
      _Pragma("unroll") for (int f = 0; f < 2; ++f)                            \
        W0N[f] = RD8(lwn, wrow + f * 16 + r16);                                \
      _Pragma("unroll") for (int g = 0; g < 4; ++g)                            \
        ALN[g] = RD8(lan, g * 16 + r16);                                       \
    }                                                                          \
    __builtin_amdgcn_s_setprio(1);                                             \
    _Pragma("unroll") for (int f = 0; f < 2; ++f)                              \
      _Pragma("unroll") for (int g = 0; g < 4; ++g) {                          \
        acc[f][4 + g] = MF8(W0C[f][0], afH[g][0], acc[f][4 + g]);              \
        acc[f][4 + g] = MF8(W0C[f][1], afH[g][1], acc[f][4 + g]);              \
      }                                                                        \
    __builtin_amdgcn_s_setprio(0);                                             \
  }

  for (int u = 0; u < 16; ++u) {
    GBODY(2 * u, wf0a, afLa, wf0b, afLb);
    GBODY(2 * u + 1, wf0b, afLb, wf0a, afLa);
  }
  GBODY(32, wf0a, afLa, wf0b, afLb);

  asm volatile("s_waitcnt vmcnt(0)" ::: "memory");

  // epilogue: out = trans + rdc*lrelu(acc/16 + fuse_b) + o_scaled   (/16 undoes W scale)
  const float rdc = rdc_scale[0];
  const int rg = lane >> 4;
#pragma unroll
  for (int f = 0; f < 4; ++f) {
#pragma unroll
    for (int r = 0; r < 4; ++r) {
      const int row = nbase + wn * 64 + f * 16 + rg * 4 + r;  // channel
      const float ob = o_scaled[row], fb = fuse_b[row];
#pragma unroll
      for (int g = 0; g < 8; ++g) {
        const int col = mbase + wm * 128 + g * 16 + r16;       // pixel
        float v = lrelu(acc[f][g][r] * 0.0625f + fb);
        const size_t idx = (size_t)row * HW_N + col;
        out[idx] = trans[idx] + rdc * v + ob;
      }
    }
  }
#undef GBODY
#undef LA
#undef LW
#undef AHALF
#undef WHALF
#undef STAGE
#undef RD8
#undef MF8
}

extern "C" void kernel_launch(void* const* d_in, const int* in_sizes, int n_in,
                              void* d_out, int out_size, void* d_ws, size_t ws_size,
                              hipStream_t stream) {
  (void)in_sizes; (void)n_in; (void)out_size; (void)ws_size;
  const float* trans = (const float*)d_in[0];
  const float* ln_w  = (const float*)d_in[1];
  const float* ln_b  = (const float*)d_in[2];
  const float* wq = (const float*)d_in[3];  const float* bq = (const float*)d_in[4];
  const float* wk = (const float*)d_in[5];  const float* bk = (const float*)d_in[6];
  const float* wv = (const float*)d_in[7];  const float* bv = (const float*)d_in[8];
  const float* wo = (const float*)d_in[9];  const float* bo = (const float*)d_in[10];
  const float* relz  = (const float*)d_in[11];
  const float* gamma = (const float*)d_in[12];
  const float* dw0 = (const float*)d_in[13]; const float* db0 = (const float*)d_in[14];
  const float* dw1 = (const float*)d_in[15]; const float* db1 = (const float*)d_in[16];
  const float* dw2 = (const float*)d_in[17]; const float* db2 = (const float*)d_in[18];
  const float* fuse_w = (const float*)d_in[19];
  const float* fuse_b = (const float*)d_in[20];
  const float* rdc    = (const float*)d_in[21];
  float* out = (float*)d_out;

  char* ws = (char*)d_ws;
  u8*    A8         = (u8*)ws;                       // 33*16384*64 = 34,603,008 B
  u8*    W8         = (u8*)(ws + 34603008);          // 33*2048*64  =  4,325,376 B
  u8*    Wd8        = (u8*)(ws + 38928384);          // 32*48*64    =     98,304 B
  float* pooled_sum = (float*)(ws + 39026688);       // 8 KB
  float* o_scaled   = (float*)(ws + 39034880);       // 8 KB

  hipMemsetAsync(pooled_sum, 0, 2048 * sizeof(float), stream);
  k_prep<<<dim3(3137), 256, 0, stream>>>(trans, fuse_w, dw0, dw1, dw2,
                                         A8, pooled_sum, W8, Wd8);
  k_dattn<<<dim3(129), 256, 0, stream>>>(A8, Wd8, dw1, dw2, db0, db1, db2, A8,
                                         pooled_sum, ln_w, ln_b, wq, bq, wk, bk,
                                         wv, bv, wo, bo, relz, gamma, o_scaled);
  k_gemm<<<dim3(512), 512, 0, stream>>>(A8, W8, trans, o_scaled, fuse_b, rdc, out);
}